// Round 7
// baseline (645.633 us; speedup 1.0000x reference)
//
#include <hip/hip_runtime.h>
#include <math.h>

// ===== ATTRIBUTION PROBE: exact round-4 kernels; writer launched 4x (idempotent)
// W_writer = (total - 202.4us) / 3

#define NQ 8192
#define D 768
#define DF4 (D/4)              /* 192 float4 per row */
#define P 64
#define K 4
#define PD 8
#define QPB 16                 /* queries per block in sim kernel */
#define NBLK (NQ/QPB)          /* 512 sim blocks */
#define ROWS_PER_WB 4          /* writer: query rows per block */
#define F4_PER_K ((PD*D)/4)    /* 1536 float4 per selected prompt block */
#define F4_PER_N ((K*PD*D)/4)  /* 6144 float4 per query row of output  */
#define SEL_ELEMS ((size_t)NQ * K * PD * D)  /* 201326592 */

typedef float f32x4 __attribute__((ext_vector_type(4)));

// ---------------- kernel 1: normalize keys -> knT4 AoS: knT4[d4*64 + key] = kn[key][4d4..4d4+3]
__global__ __launch_bounds__(256) void normalize_keys(const float* __restrict__ keys,
                                                      f32x4* __restrict__ knT4,
                                                      int* __restrict__ g_counts) {
    int b = blockIdx.x;           // key row
    int t = threadIdx.x;
    if (b == 0 && t < P) g_counts[t] = 0;
    __shared__ float red[256];
    float ss = 0.f;
    for (int j = t; j < D; j += 256) { float v = keys[b * D + j]; ss = fmaf(v, v, ss); }
    red[t] = ss; __syncthreads();
    for (int s = 128; s > 0; s >>= 1) { if (t < s) red[t] += red[t + s]; __syncthreads(); }
    float inv = 1.f / fmaxf(sqrtf(red[0]), 1e-12f);
    if (t < DF4) {
        f32x4 v;
        v.x = keys[b * D + 4 * t + 0] * inv;
        v.y = keys[b * D + 4 * t + 1] * inv;
        v.z = keys[b * D + 4 * t + 2] * inv;
        v.w = keys[b * D + 4 * t + 3] * inv;
        knT4[t * P + b] = v;
    }
}

// ---------------- kernel 2: sims, per-query top-4 vote, per-key column sums (for loss)
__global__ __launch_bounds__(256) void sim_topk(const float* __restrict__ q,
                                                const f32x4* __restrict__ knT4,
                                                int* __restrict__ g_counts,
                                                float* __restrict__ colpartial) {
    __shared__ float4 qt[QPB * DF4];      // 48 KB: 16 query rows
    __shared__ float  simw[4][QPB][P];    // 16 KB: per-wave partial dots
    __shared__ float  colw[4][P];         // per-wave column sums
    __shared__ int    cnt[P];
    int t = threadIdx.x;
    int w = t >> 6, lane = t & 63;
    int qbase = blockIdx.x * QPB;

    const float4* q4 = (const float4*)q + (size_t)qbase * DF4;
    #pragma unroll
    for (int i = 0; i < (QPB * DF4) / 256; ++i) qt[t + i * 256] = q4[t + i * 256];
    if (t < P) cnt[t] = 0;
    __syncthreads();

    float acc[QPB];
    #pragma unroll
    for (int i = 0; i < QPB; ++i) acc[i] = 0.f;
    int d4base = w * 48;                  // float4 index base within a row
    const f32x4* kq = knT4 + (size_t)d4base * P;   // this wave's quarter
    #pragma unroll 4
    for (int d4 = 0; d4 < 48; ++d4) {
        f32x4 kv = kq[d4 * P + lane];     // coalesced 1KB wave load, 4 in flight
        #pragma unroll
        for (int qi = 0; qi < QPB; ++qi) {
            float4 v = qt[qi * DF4 + d4base + d4];    // uniform -> LDS broadcast
            acc[qi] = fmaf(v.x, kv.x, fmaf(v.y, kv.y, fmaf(v.z, kv.z, fmaf(v.w, kv.w, acc[qi]))));
        }
    }
    #pragma unroll
    for (int qi = 0; qi < QPB; ++qi) simw[w][qi][lane] = acc[qi];
    __syncthreads();

    float colacc = 0.f;
    #pragma unroll
    for (int s = 0; s < 4; ++s) {
        int qi = w * 4 + s;
        float dot = simw[0][qi][lane] + simw[1][qi][lane] + simw[2][qi][lane] + simw[3][qi][lane];
        float ss = 0.f;
        #pragma unroll
        for (int j = 0; j < 3; ++j) {
            float4 v = qt[qi * DF4 + lane + j * 64];
            ss = fmaf(v.x, v.x, fmaf(v.y, v.y, fmaf(v.z, v.z, fmaf(v.w, v.w, ss))));
        }
        #pragma unroll
        for (int off = 32; off > 0; off >>= 1) ss += __shfl_xor(ss, off);
        float inv = 1.f / fmaxf(sqrtf(ss), 1e-12f);
        float sim = dot * inv;
        colacc += sim;
        float mv = sim;
        int w0, w1, w2, w3;
        #pragma unroll
        for (int r = 0; r < 4; ++r) {
            float v = mv; int idx = lane;
            #pragma unroll
            for (int off = 32; off > 0; off >>= 1) {
                float ov = __shfl_xor(v, off);
                int   oi = __shfl_xor(idx, off);
                if (ov > v || (ov == v && oi < idx)) { v = ov; idx = oi; }
            }
            if (r == 0) w0 = idx; else if (r == 1) w1 = idx; else if (r == 2) w2 = idx; else w3 = idx;
            if (lane == idx) mv = -INFINITY;
        }
        if (lane == 0) {
            atomicAdd(&cnt[w0], 1); atomicAdd(&cnt[w1], 1);
            atomicAdd(&cnt[w2], 1); atomicAdd(&cnt[w3], 1);
        }
    }
    colw[w][lane] = colacc;
    __syncthreads();

    if (t < P) {
        atomicAdd(&g_counts[t], cnt[t]);
        colpartial[(size_t)blockIdx.x * P + t] = colw[0][t] + colw[1][t] + colw[2][t] + colw[3][t];
    }
}

// ---------------- kernel 3: reduce column sums, top-4 of counts, loss
__global__ __launch_bounds__(256) void finalize(const float* __restrict__ colpartial,
                                                const int* __restrict__ g_counts,
                                                int* __restrict__ top_idx,
                                                float* __restrict__ loss_out) {
    __shared__ float colg[4][P];
    __shared__ float colsum[P];
    int t = threadIdx.x;
    int key = t & 63, grp = t >> 6;       // 4 groups x 128 blocks each
    float s = 0.f;
    for (int b = grp * (NBLK / 4); b < (grp + 1) * (NBLK / 4); ++b)
        s += colpartial[(size_t)b * P + key];
    colg[grp][key] = s;
    __syncthreads();
    if (t < P) colsum[t] = colg[0][t] + colg[1][t] + colg[2][t] + colg[3][t];
    __syncthreads();
    if (t == 0) {
        int c[P];
        #pragma unroll
        for (int i = 0; i < P; ++i) c[i] = g_counts[i];
        float loss = 0.f;
        for (int r = 0; r < K; ++r) {
            int best = 0, bv = c[0];
            for (int i = 1; i < P; ++i) if (c[i] > bv) { bv = c[i]; best = i; }
            top_idx[r] = best; loss += colsum[best]; c[best] = -1;
        }
        loss_out[0] = loss / (float)NQ;
    }
}

// ---------------- kernel 4: broadcast-write selected prompts, 4 query rows per block
__global__ __launch_bounds__(256) void writer(const float* __restrict__ prompts,
                                              const int* __restrict__ top_idx,
                                              float* __restrict__ out) {
    int b = blockIdx.x;                   // 2048 blocks
    int t = threadIdx.x;
    int i0 = top_idx[0], i1 = top_idx[1], i2 = top_idx[2], i3 = top_idx[3];
    const f32x4* p4 = (const f32x4*)prompts;
    f32x4* o4 = (f32x4*)out + (size_t)b * ROWS_PER_WB * F4_PER_N;
    #pragma unroll
    for (int k = 0; k < K; ++k) {
        int src = (k == 0) ? i0 : (k == 1) ? i1 : (k == 2) ? i2 : i3;
        const f32x4* sp = p4 + (size_t)src * F4_PER_K;
        #pragma unroll
        for (int jj = 0; jj < 6; ++jj) {
            int off = jj * 256 + t;        // 0..1535, contiguous per k
            f32x4 v = sp[off];
            #pragma unroll
            for (int r = 0; r < ROWS_PER_WB; ++r)
                o4[(size_t)r * F4_PER_N + k * F4_PER_K + off] = v;
        }
    }
}

extern "C" void kernel_launch(void* const* d_in, const int* in_sizes, int n_in,
                              void* d_out, int out_size, void* d_ws, size_t ws_size,
                              hipStream_t stream) {
    const float* queries = (const float*)d_in[0];   // [8192, 768]
    const float* keys    = (const float*)d_in[1];   // [64, 768]
    const float* prompts = (const float*)d_in[2];   // [64, 8, 768]
    float* out = (float*)d_out;                     // [8192*32*768] + [1]
    float* ws  = (float*)d_ws;

    f32x4* knT4       = (f32x4*)ws;               // 192*64 float4 = 49152 floats
    float* colpartial = ws + 49152;               // 512*64 = 32768 floats
    int*   counts     = (int*)(ws + 49152 + 32768);       // 64 ints
    int*   top_idx    = (int*)(ws + 49152 + 32768 + 64);  // 4 ints

    normalize_keys<<<P, 256, 0, stream>>>(keys, knT4, counts);
    sim_topk<<<NBLK, 256, 0, stream>>>(queries, knT4, counts, colpartial);
    finalize<<<1, 256, 0, stream>>>(colpartial, counts, top_idx, out + SEL_ELEMS);
    // Idempotent writer launched 4x: (total - baseline_202.4) / 3 = per-writer duration.
    writer<<<NQ / ROWS_PER_WB, 256, 0, stream>>>(prompts, top_idx, out);
    writer<<<NQ / ROWS_PER_WB, 256, 0, stream>>>(prompts, top_idx, out);
    writer<<<NQ / ROWS_PER_WB, 256, 0, stream>>>(prompts, top_idx, out);
    writer<<<NQ / ROWS_PER_WB, 256, 0, stream>>>(prompts, top_idx, out);
}

// Round 8
// 233.188 us; speedup vs baseline: 2.7687x; 2.7687x over previous
//
#include <hip/hip_runtime.h>
#include <math.h>

#define NQ 8192
#define D 768
#define DF4 (D/4)              /* 192 float4 per row */
#define QSTRIDE 193            /* padded LDS row stride (float4) -> bank rotation */
#define P 64
#define K 4
#define PD 8
#define QPB 16                 /* queries per block in sim kernel */
#define NBLK (NQ/QPB)          /* 512 sim blocks */
#define ROWS_PER_WB 16         /* writer: query rows per block */
#define F4_PER_K ((PD*D)/4)    /* 1536 float4 per selected prompt block */
#define F4_PER_N ((K*PD*D)/4)  /* 6144 float4 per query row of output  */
#define SEL_ELEMS ((size_t)NQ * K * PD * D)  /* 201326592 */

typedef float f32x4 __attribute__((ext_vector_type(4)));

// ---------------- kernel 1: normalize keys -> knT4 AoS: knT4[d4*64 + key]
__global__ __launch_bounds__(256) void normalize_keys(const float* __restrict__ keys,
                                                      f32x4* __restrict__ knT4,
                                                      int* __restrict__ g_counts) {
    int b = blockIdx.x;           // key row
    int t = threadIdx.x;
    if (b == 0 && t < P) g_counts[t] = 0;
    __shared__ float red[256];
    float ss = 0.f;
    for (int j = t; j < D; j += 256) { float v = keys[b * D + j]; ss = fmaf(v, v, ss); }
    red[t] = ss; __syncthreads();
    for (int s = 128; s > 0; s >>= 1) { if (t < s) red[t] += red[t + s]; __syncthreads(); }
    float inv = 1.f / fmaxf(sqrtf(red[0]), 1e-12f);
    if (t < DF4) {
        f32x4 v;
        v.x = keys[b * D + 4 * t + 0] * inv;
        v.y = keys[b * D + 4 * t + 1] * inv;
        v.z = keys[b * D + 4 * t + 2] * inv;
        v.w = keys[b * D + 4 * t + 3] * inv;
        knT4[t * P + b] = v;
    }
}

// ---------------- kernel 2 (v3): lane-parallel LDS dot layout.
// Thread t: query qi = t&15, key group kg = t>>4 (keys 4kg..4kg+3), full-D dots.
// q reads from LDS hit 16 DISTINCT padded rows per instr (no broadcast waste);
// key reads are global 16B-broadcast lines (L1-resident).
__global__ __launch_bounds__(256) void sim_topk(const float* __restrict__ q,
                                                const f32x4* __restrict__ knT4,
                                                int* __restrict__ g_counts,
                                                float* __restrict__ colpartial) {
    __shared__ float4 qt[QPB * QSTRIDE];  // ~49.4 KB, padded rows
    __shared__ float4 simq4[QPB * 17];    // sim matrix bounce, padded
    __shared__ float  colw[4][P];
    __shared__ int    cnt[P];
    int t = threadIdx.x;
    int w = t >> 6, lane = t & 63;
    int qbase = blockIdx.x * QPB;

    // stage 16 query rows (coalesced global, padded LDS rows)
    const float4* q4 = (const float4*)q + (size_t)qbase * DF4;
    #pragma unroll
    for (int i = 0; i < (QPB * DF4) / 256; ++i) {
        int idx = t + i * 256;
        int qi = idx / DF4, j = idx - qi * DF4;
        qt[qi * QSTRIDE + j] = q4[idx];
    }
    if (t < P) cnt[t] = 0;
    __syncthreads();

    // full-D dots: 1 query x 4 keys per thread
    int qi = t & 15, kg = t >> 4;
    const float4* qrow = qt + qi * QSTRIDE;
    const f32x4* kbase = knT4 + 4 * kg;
    float a0 = 0.f, a1 = 0.f, a2 = 0.f, a3 = 0.f;
    #pragma unroll 4
    for (int d4 = 0; d4 < DF4; ++d4) {
        float4 qv = qrow[d4];                 // ds_read_b128, 16 distinct rows
        f32x4 k0 = kbase[d4 * P + 0];
        f32x4 k1 = kbase[d4 * P + 1];
        f32x4 k2 = kbase[d4 * P + 2];
        f32x4 k3 = kbase[d4 * P + 3];
        a0 = fmaf(qv.x, k0.x, fmaf(qv.y, k0.y, fmaf(qv.z, k0.z, fmaf(qv.w, k0.w, a0))));
        a1 = fmaf(qv.x, k1.x, fmaf(qv.y, k1.y, fmaf(qv.z, k1.z, fmaf(qv.w, k1.w, a1))));
        a2 = fmaf(qv.x, k2.x, fmaf(qv.y, k2.y, fmaf(qv.z, k2.z, fmaf(qv.w, k2.w, a2))));
        a3 = fmaf(qv.x, k3.x, fmaf(qv.y, k3.y, fmaf(qv.z, k3.z, fmaf(qv.w, k3.w, a3))));
    }
    {
        float4 v; v.x = a0; v.y = a1; v.z = a2; v.w = a3;
        simq4[qi * 17 + kg] = v;              // keys 4kg..4kg+3 of query qi
    }
    __syncthreads();

    // wave w finalizes queries w*4 .. w*4+3 (lane = key), same as proven R4 epilogue
    const float* simq = (const float*)simq4;  // row stride 68 floats
    float colacc = 0.f;
    #pragma unroll
    for (int s = 0; s < 4; ++s) {
        int qe = w * 4 + s;
        float dot = simq[qe * 68 + lane];
        // ssq via lane-split over the row (3 float4 per lane) + butterfly
        float ss = 0.f;
        #pragma unroll
        for (int j = 0; j < 3; ++j) {
            float4 v = qt[qe * QSTRIDE + lane + j * 64];
            ss = fmaf(v.x, v.x, fmaf(v.y, v.y, fmaf(v.z, v.z, fmaf(v.w, v.w, ss))));
        }
        #pragma unroll
        for (int off = 32; off > 0; off >>= 1) ss += __shfl_xor(ss, off);
        float inv = 1.f / fmaxf(sqrtf(ss), 1e-12f);
        float sim = dot * inv;
        colacc += sim;
        // top-4 over 64 lanes, ties -> lowest key index (matches lax.top_k)
        float mv = sim;
        int w0, w1, w2, w3;
        #pragma unroll
        for (int r = 0; r < 4; ++r) {
            float v = mv; int idx = lane;
            #pragma unroll
            for (int off = 32; off > 0; off >>= 1) {
                float ov = __shfl_xor(v, off);
                int   oi = __shfl_xor(idx, off);
                if (ov > v || (ov == v && oi < idx)) { v = ov; idx = oi; }
            }
            if (r == 0) w0 = idx; else if (r == 1) w1 = idx; else if (r == 2) w2 = idx; else w3 = idx;
            if (lane == idx) mv = -INFINITY;
        }
        if (lane == 0) {
            atomicAdd(&cnt[w0], 1); atomicAdd(&cnt[w1], 1);
            atomicAdd(&cnt[w2], 1); atomicAdd(&cnt[w3], 1);
        }
    }
    colw[w][lane] = colacc;
    __syncthreads();

    if (t < P) {
        atomicAdd(&g_counts[t], cnt[t]);
        colpartial[(size_t)blockIdx.x * P + t] = colw[0][t] + colw[1][t] + colw[2][t] + colw[3][t];
    }
}

// ---------------- kernel 3: reduce column sums, top-4 of counts, loss
__global__ __launch_bounds__(256) void finalize(const float* __restrict__ colpartial,
                                                const int* __restrict__ g_counts,
                                                int* __restrict__ top_idx,
                                                float* __restrict__ loss_out) {
    __shared__ float colg[4][P];
    __shared__ float colsum[P];
    int t = threadIdx.x;
    int key = t & 63, grp = t >> 6;       // 4 groups x 128 blocks each
    float s = 0.f;
    for (int b = grp * (NBLK / 4); b < (grp + 1) * (NBLK / 4); ++b)
        s += colpartial[(size_t)b * P + key];
    colg[grp][key] = s;
    __syncthreads();
    if (t < P) colsum[t] = colg[0][t] + colg[1][t] + colg[2][t] + colg[3][t];
    __syncthreads();
    if (t == 0) {
        int c[P];
        #pragma unroll
        for (int i = 0; i < P; ++i) c[i] = g_counts[i];
        float loss = 0.f;
        for (int r = 0; r < K; ++r) {
            int best = 0, bv = c[0];
            for (int i = 1; i < P; ++i) if (c[i] > bv) { bv = c[i]; best = i; }  // > keeps lowest idx on tie
            top_idx[r] = best; loss += colsum[best]; c[best] = -1;
        }
        loss_out[0] = loss / (float)NQ;
    }
}

// ---------------- kernel 4: broadcast-write, 16 rows/block, register-staged.
// Per k: 6 loads held in regs, 96 stores (1:16 load:store) -> L2 reads 196->49 MB.
__global__ __launch_bounds__(256) void writer(const float* __restrict__ prompts,
                                              const int* __restrict__ top_idx,
                                              float* __restrict__ out) {
    int b = blockIdx.x;                   // 512 blocks
    int t = threadIdx.x;
    int i0 = top_idx[0], i1 = top_idx[1], i2 = top_idx[2], i3 = top_idx[3];
    const f32x4* p4 = (const f32x4*)prompts;
    f32x4* o4 = (f32x4*)out + (size_t)b * ROWS_PER_WB * F4_PER_N;
    #pragma unroll
    for (int k = 0; k < K; ++k) {
        int src = (k == 0) ? i0 : (k == 1) ? i1 : (k == 2) ? i2 : i3;
        const f32x4* sp = p4 + (size_t)src * F4_PER_K;
        f32x4 v0 = sp[0 * 256 + t], v1 = sp[1 * 256 + t], v2 = sp[2 * 256 + t];
        f32x4 v3 = sp[3 * 256 + t], v4 = sp[4 * 256 + t], v5 = sp[5 * 256 + t];
        #pragma unroll
        for (int r = 0; r < ROWS_PER_WB; ++r) {
            f32x4* dst = o4 + (size_t)r * F4_PER_N + k * F4_PER_K;
            dst[0 * 256 + t] = v0; dst[1 * 256 + t] = v1; dst[2 * 256 + t] = v2;
            dst[3 * 256 + t] = v3; dst[4 * 256 + t] = v4; dst[5 * 256 + t] = v5;
        }
    }
}

extern "C" void kernel_launch(void* const* d_in, const int* in_sizes, int n_in,
                              void* d_out, int out_size, void* d_ws, size_t ws_size,
                              hipStream_t stream) {
    const float* queries = (const float*)d_in[0];   // [8192, 768]
    const float* keys    = (const float*)d_in[1];   // [64, 768]
    const float* prompts = (const float*)d_in[2];   // [64, 8, 768]
    float* out = (float*)d_out;                     // [8192*32*768] + [1]
    float* ws  = (float*)d_ws;

    f32x4* knT4       = (f32x4*)ws;               // 192*64 float4 = 49152 floats
    float* colpartial = ws + 49152;               // 512*64 = 32768 floats
    int*   counts     = (int*)(ws + 49152 + 32768);       // 64 ints
    int*   top_idx    = (int*)(ws + 49152 + 32768 + 64);  // 4 ints

    normalize_keys<<<P, 256, 0, stream>>>(keys, knT4, counts);
    sim_topk<<<NBLK, 256, 0, stream>>>(queries, knT4, counts, colpartial);
    finalize<<<1, 256, 0, stream>>>(colpartial, counts, top_idx, out + SEL_ELEMS);
    writer<<<NQ / ROWS_PER_WB, 256, 0, stream>>>(prompts, top_idx, out);
}

// Round 9
// 214.130 us; speedup vs baseline: 3.0151x; 1.0890x over previous
//
#include <hip/hip_runtime.h>
#include <math.h>

#define NQ 8192
#define D 768
#define DF4 (D/4)              /* 192 float4 per row */
#define P 64
#define K 4
#define PD 8
#define QPB 16                 /* queries per block in sim kernel */
#define NBLK (NQ/QPB)          /* 512 sim blocks */
#define ROWS_PER_WB 4          /* writer: query rows per block */
#define F4_PER_K ((PD*D)/4)    /* 1536 float4 per selected prompt block */
#define F4_PER_N ((K*PD*D)/4)  /* 6144 float4 per query row of output  */
#define SEL_ELEMS ((size_t)NQ * K * PD * D)  /* 201326592 */

typedef float f32x4 __attribute__((ext_vector_type(4)));

// ---------------- kernel 1: normalize keys -> knT4 AoS: knT4[d4*64 + key]
__global__ __launch_bounds__(256) void normalize_keys(const float* __restrict__ keys,
                                                      f32x4* __restrict__ knT4,
                                                      int* __restrict__ g_counts) {
    int b = blockIdx.x;           // key row
    int t = threadIdx.x;
    if (b == 0 && t < P) g_counts[t] = 0;
    __shared__ float red[256];
    float ss = 0.f;
    for (int j = t; j < D; j += 256) { float v = keys[b * D + j]; ss = fmaf(v, v, ss); }
    red[t] = ss; __syncthreads();
    for (int s = 128; s > 0; s >>= 1) { if (t < s) red[t] += red[t + s]; __syncthreads(); }
    float inv = 1.f / fmaxf(sqrtf(red[0]), 1e-12f);
    if (t < DF4) {
        f32x4 v;
        v.x = keys[b * D + 4 * t + 0] * inv;
        v.y = keys[b * D + 4 * t + 1] * inv;
        v.z = keys[b * D + 4 * t + 2] * inv;
        v.w = keys[b * D + 4 * t + 3] * inv;
        knT4[t * P + b] = v;
    }
}

// ---------------- kernel 2: sims, per-query top-4 vote, per-key column sums
// (exact round-4 version: measured S ~= 36us)
__global__ __launch_bounds__(256) void sim_topk(const float* __restrict__ q,
                                                const f32x4* __restrict__ knT4,
                                                int* __restrict__ g_counts,
                                                float* __restrict__ colpartial) {
    __shared__ float4 qt[QPB * DF4];      // 48 KB: 16 query rows
    __shared__ float  simw[4][QPB][P];    // 16 KB: per-wave partial dots
    __shared__ float  colw[4][P];         // per-wave column sums
    __shared__ int    cnt[P];
    int t = threadIdx.x;
    int w = t >> 6, lane = t & 63;
    int qbase = blockIdx.x * QPB;

    const float4* q4 = (const float4*)q + (size_t)qbase * DF4;
    #pragma unroll
    for (int i = 0; i < (QPB * DF4) / 256; ++i) qt[t + i * 256] = q4[t + i * 256];
    if (t < P) cnt[t] = 0;
    __syncthreads();

    float acc[QPB];
    #pragma unroll
    for (int i = 0; i < QPB; ++i) acc[i] = 0.f;
    int d4base = w * 48;                  // float4 index base within a row
    const f32x4* kq = knT4 + (size_t)d4base * P;   // this wave's quarter
    #pragma unroll 4
    for (int d4 = 0; d4 < 48; ++d4) {
        f32x4 kv = kq[d4 * P + lane];     // coalesced 1KB wave load, 4 in flight
        #pragma unroll
        for (int qi = 0; qi < QPB; ++qi) {
            float4 v = qt[qi * DF4 + d4base + d4];    // uniform -> LDS broadcast
            acc[qi] = fmaf(v.x, kv.x, fmaf(v.y, kv.y, fmaf(v.z, kv.z, fmaf(v.w, kv.w, acc[qi]))));
        }
    }
    #pragma unroll
    for (int qi = 0; qi < QPB; ++qi) simw[w][qi][lane] = acc[qi];
    __syncthreads();

    float colacc = 0.f;
    #pragma unroll
    for (int s = 0; s < 4; ++s) {
        int qi = w * 4 + s;
        float dot = simw[0][qi][lane] + simw[1][qi][lane] + simw[2][qi][lane] + simw[3][qi][lane];
        float ss = 0.f;
        #pragma unroll
        for (int j = 0; j < 3; ++j) {
            float4 v = qt[qi * DF4 + lane + j * 64];
            ss = fmaf(v.x, v.x, fmaf(v.y, v.y, fmaf(v.z, v.z, fmaf(v.w, v.w, ss))));
        }
        #pragma unroll
        for (int off = 32; off > 0; off >>= 1) ss += __shfl_xor(ss, off);
        float inv = 1.f / fmaxf(sqrtf(ss), 1e-12f);
        float sim = dot * inv;
        colacc += sim;
        float mv = sim;
        int w0, w1, w2, w3;
        #pragma unroll
        for (int r = 0; r < 4; ++r) {
            float v = mv; int idx = lane;
            #pragma unroll
            for (int off = 32; off > 0; off >>= 1) {
                float ov = __shfl_xor(v, off);
                int   oi = __shfl_xor(idx, off);
                if (ov > v || (ov == v && oi < idx)) { v = ov; idx = oi; }
            }
            if (r == 0) w0 = idx; else if (r == 1) w1 = idx; else if (r == 2) w2 = idx; else w3 = idx;
            if (lane == idx) mv = -INFINITY;
        }
        if (lane == 0) {
            atomicAdd(&cnt[w0], 1); atomicAdd(&cnt[w1], 1);
            atomicAdd(&cnt[w2], 1); atomicAdd(&cnt[w3], 1);
        }
    }
    colw[w][lane] = colacc;
    __syncthreads();

    if (t < P) {
        atomicAdd(&g_counts[t], cnt[t]);
        colpartial[(size_t)blockIdx.x * P + t] = colw[0][t] + colw[1][t] + colw[2][t] + colw[3][t];
    }
}

// ---------------- kernel 3: reduce column sums, top-4 of counts, loss
__global__ __launch_bounds__(256) void finalize(const float* __restrict__ colpartial,
                                                const int* __restrict__ g_counts,
                                                int* __restrict__ top_idx,
                                                float* __restrict__ loss_out) {
    __shared__ float colg[4][P];
    __shared__ float colsum[P];
    int t = threadIdx.x;
    int key = t & 63, grp = t >> 6;       // 4 groups x 128 blocks each
    float s = 0.f;
    for (int b = grp * (NBLK / 4); b < (grp + 1) * (NBLK / 4); ++b)
        s += colpartial[(size_t)b * P + key];
    colg[grp][key] = s;
    __syncthreads();
    if (t < P) colsum[t] = colg[0][t] + colg[1][t] + colg[2][t] + colg[3][t];
    __syncthreads();
    if (t == 0) {
        int c[P];
        #pragma unroll
        for (int i = 0; i < P; ++i) c[i] = g_counts[i];
        float loss = 0.f;
        for (int r = 0; r < K; ++r) {
            int best = 0, bv = c[0];
            for (int i = 1; i < P; ++i) if (c[i] > bv) { bv = c[i]; best = i; }
            top_idx[r] = best; loss += colsum[best]; c[best] = -1;
        }
        loss_out[0] = loss / (float)NQ;
    }
}

// ---------------- kernel 4: broadcast-write, 4 rows/block, STRICTLY ASCENDING stores.
// Stage all 24 f32x4 per thread, then store r-outer/k-middle/jj-inner so each block
// emits ONE monotone 96KB write stream (matches the 6.8 TB/s fill's pattern).
__global__ __launch_bounds__(256) void writer(const float* __restrict__ prompts,
                                              const int* __restrict__ top_idx,
                                              float* __restrict__ out) {
    int b = blockIdx.x;                   // 2048 blocks
    int t = threadIdx.x;
    const f32x4* p4 = (const f32x4*)prompts;
    f32x4 v[K][6];
    #pragma unroll
    for (int k = 0; k < K; ++k) {
        const f32x4* sp = p4 + (size_t)top_idx[k] * F4_PER_K;
        #pragma unroll
        for (int j = 0; j < 6; ++j) v[k][j] = sp[j * 256 + t];
    }
    f32x4* o4 = (f32x4*)out + (size_t)b * ROWS_PER_WB * F4_PER_N;
    #pragma unroll
    for (int r = 0; r < ROWS_PER_WB; ++r) {
        f32x4* dst = o4 + (size_t)r * F4_PER_N;
        #pragma unroll
        for (int k = 0; k < K; ++k) {
            #pragma unroll
            for (int j = 0; j < 6; ++j)
                dst[k * F4_PER_K + j * 256 + t] = v[k][j];
        }
    }
}

extern "C" void kernel_launch(void* const* d_in, const int* in_sizes, int n_in,
                              void* d_out, int out_size, void* d_ws, size_t ws_size,
                              hipStream_t stream) {
    const float* queries = (const float*)d_in[0];   // [8192, 768]
    const float* keys    = (const float*)d_in[1];   // [64, 768]
    const float* prompts = (const float*)d_in[2];   // [64, 8, 768]
    float* out = (float*)d_out;                     // [8192*32*768] + [1]
    float* ws  = (float*)d_ws;

    f32x4* knT4       = (f32x4*)ws;               // 192*64 float4 = 49152 floats
    float* colpartial = ws + 49152;               // 512*64 = 32768 floats
    int*   counts     = (int*)(ws + 49152 + 32768);       // 64 ints
    int*   top_idx    = (int*)(ws + 49152 + 32768 + 64);  // 4 ints

    normalize_keys<<<P, 256, 0, stream>>>(keys, knT4, counts);
    sim_topk<<<NBLK, 256, 0, stream>>>(queries, knT4, counts, colpartial);
    finalize<<<1, 256, 0, stream>>>(colpartial, counts, top_idx, out + SEL_ELEMS);
    writer<<<NQ / ROWS_PER_WB, 256, 0, stream>>>(prompts, top_idx, out);
}